// Round 4
// baseline (292.206 us; speedup 1.0000x reference)
//
#include <hip/hip_runtime.h>
#include <hip/hip_bf16.h>

typedef __attribute__((ext_vector_type(8))) short short8;
typedef __attribute__((ext_vector_type(4))) float floatx4;
typedef unsigned short u16;

__device__ __forceinline__ float b2f(u16 u) {
    unsigned int x = ((unsigned int)u) << 16;
    float f;
    __builtin_memcpy(&f, &x, 4);
    return f;
}
__device__ __forceinline__ u16 f2b(float f) {
    unsigned int x;
    __builtin_memcpy(&x, &f, 4);
    unsigned int lsb = (x >> 16) & 1u;
    x += 0x7fffu + lsb;
    return (u16)(x >> 16);
}

// ------------- transpose fp32 -> bf16, batched: out[C][R] = bf16(in[R][C]) -------------
__global__ __launch_bounds__(256) void transpose_f2b(const float* __restrict__ in,
                                                     u16* __restrict__ out,
                                                     int R, int C, long ibs, long obs) {
    __shared__ float tile[32][33];
    int b = blockIdx.z;
    const float* ip = in + (long)b * ibs;
    u16* op = out + (long)b * obs;
    int c0 = blockIdx.x * 32, r0 = blockIdx.y * 32;
    int tx = threadIdx.x & 31, ty = threadIdx.x >> 5;  // ty in 0..7
    for (int j = 0; j < 32; j += 8)
        tile[ty + j][tx] = ip[(long)(r0 + ty + j) * C + c0 + tx];
    __syncthreads();
    for (int j = 0; j < 32; j += 8)
        op[(long)(c0 + ty + j) * R + r0 + tx] = f2b(tile[tx][ty + j]);
}

// ---- GEMM 128x128 tile (m93 structure): C[M][N] = A[M][K] @ Bt[N][K]^T + bias ----
#define TP2 40
template <int A_F32, int OUT_F32>
__global__ __launch_bounds__(256) void gemm128(const void* __restrict__ Av,
                                               const u16* __restrict__ Bt,
                                               const float* __restrict__ bias,
                                               void* __restrict__ Cv,
                                               int M, int N, int K) {
    __shared__ __align__(16) u16 lA[128 * TP2];
    __shared__ __align__(16) u16 lB[128 * TP2];
    int tid = threadIdx.x, lane = tid & 63, w = tid >> 6;
    int wr = w >> 1, wc = w & 1;
    int m0 = blockIdx.x * 128, n0 = blockIdx.y * 128;
    floatx4 acc[4][4] = {};
    int srow = tid >> 2, sseg = (tid & 3) * 8;
    const int lr = lane & 15, kg = lane >> 4, kb = kg * 8;
    for (int k0 = 0; k0 < K; k0 += 32) {
        if (A_F32) {
            const float* A = (const float*)Av;
            #pragma unroll
            for (int half = 0; half < 2; half++) {
                int row = half * 64 + srow;
                const float* ap = &A[(long)(m0 + row) * K + k0 + sseg];
                float4 f0 = *(const float4*)ap;
                float4 f1 = *(const float4*)(ap + 4);
                short8 s;
                s[0] = (short)f2b(f0.x); s[1] = (short)f2b(f0.y);
                s[2] = (short)f2b(f0.z); s[3] = (short)f2b(f0.w);
                s[4] = (short)f2b(f1.x); s[5] = (short)f2b(f1.y);
                s[6] = (short)f2b(f1.z); s[7] = (short)f2b(f1.w);
                *(short8*)&lA[row * TP2 + sseg] = s;
            }
        } else {
            const u16* A = (const u16*)Av;
            *(short8*)&lA[srow * TP2 + sseg] =
                *(const short8*)&A[(long)(m0 + srow) * K + k0 + sseg];
            *(short8*)&lA[(64 + srow) * TP2 + sseg] =
                *(const short8*)&A[(long)(m0 + 64 + srow) * K + k0 + sseg];
        }
        *(short8*)&lB[srow * TP2 + sseg] =
            *(const short8*)&Bt[(long)(n0 + srow) * K + k0 + sseg];
        *(short8*)&lB[(64 + srow) * TP2 + sseg] =
            *(const short8*)&Bt[(long)(n0 + 64 + srow) * K + k0 + sseg];
        __syncthreads();
        short8 af[4], bf[4];
        #pragma unroll
        for (int mi = 0; mi < 4; mi++)
            af[mi] = *(const short8*)&lA[(wr * 64 + mi * 16 + lr) * TP2 + kb];
        #pragma unroll
        for (int ni = 0; ni < 4; ni++)
            bf[ni] = *(const short8*)&lB[(wc * 64 + ni * 16 + lr) * TP2 + kb];
        #pragma unroll
        for (int mi = 0; mi < 4; mi++)
            #pragma unroll
            for (int ni = 0; ni < 4; ni++)
                acc[mi][ni] = __builtin_amdgcn_mfma_f32_16x16x32_bf16(af[mi], bf[ni], acc[mi][ni], 0, 0, 0);
        __syncthreads();
    }
    #pragma unroll
    for (int mi = 0; mi < 4; mi++)
        #pragma unroll
        for (int ni = 0; ni < 4; ni++) {
            int n = n0 + wc * 64 + ni * 16 + lr;
            float bv = bias[n];
            #pragma unroll
            for (int r = 0; r < 4; r++) {
                int m = m0 + wr * 64 + mi * 16 + kg * 4 + r;
                float cv = acc[mi][ni][r] + bv;
                if (OUT_F32) ((float*)Cv)[(long)m * N + n] = cv;
                else ((u16*)Cv)[(long)m * N + n] = f2b(cv);
            }
        }
}

// --------- fused bilinear-resize (16->32, half-pixel) + channel-first LN (eps 1e-6) ---------
__global__ __launch_bounds__(256) void ln1_resize(const u16* __restrict__ t_lo,
                                                  const float* __restrict__ lnw,
                                                  const float* __restrict__ lnb,
                                                  u16* __restrict__ q_in) {
    int b = blockIdx.z, oh = blockIdx.y, ow = blockIdx.x;
    float sy = oh * 0.5f - 0.25f;
    int iy = (int)floorf(sy);
    float fy = sy - (float)iy;
    int y0 = min(max(iy, 0), 15), y1 = min(max(iy + 1, 0), 15);
    float sx = ow * 0.5f - 0.25f;
    int ix = (int)floorf(sx);
    float fx = sx - (float)ix;
    int x0 = min(max(ix, 0), 15), x1 = min(max(ix + 1, 0), 15);
    float w00 = (1.f - fy) * (1.f - fx), w01 = (1.f - fy) * fx;
    float w10 = fy * (1.f - fx), w11 = fy * fx;
    long base = (long)b * 256 * 768;
    long i00 = base + (long)(y0 * 16 + x0) * 768;
    long i01 = base + (long)(y0 * 16 + x1) * 768;
    long i10 = base + (long)(y1 * 16 + x0) * 768;
    long i11 = base + (long)(y1 * 16 + x1) * 768;
    int tid = threadIdx.x;
    float v[3], s = 0.f, sq = 0.f;
    for (int j = 0; j < 3; j++) {
        int ch = tid + j * 256;
        float val = w00 * b2f(t_lo[i00 + ch]) + w01 * b2f(t_lo[i01 + ch]) +
                    w10 * b2f(t_lo[i10 + ch]) + w11 * b2f(t_lo[i11 + ch]);
        v[j] = val;
        s += val;
        sq += val * val;
    }
    __shared__ float rs[4], rq[4];
    for (int off = 32; off >= 1; off >>= 1) {
        s += __shfl_down(s, off);
        sq += __shfl_down(sq, off);
    }
    int lane = tid & 63, wid = tid >> 6;
    if (lane == 0) { rs[wid] = s; rq[wid] = sq; }
    __syncthreads();
    if (tid == 0) {
        rs[0] = rs[0] + rs[1] + rs[2] + rs[3];
        rq[0] = rq[0] + rq[1] + rq[2] + rq[3];
    }
    __syncthreads();
    float mean = rs[0] * (1.f / 768.f);
    float var = rq[0] * (1.f / 768.f) - mean * mean;
    float rstd = rsqrtf(var + 1e-6f);
    long orow = ((long)b * 1024 + oh * 32 + ow) * 768;
    for (int j = 0; j < 3; j++) {
        int ch = tid + j * 256;
        float o = (v[j] - mean) * rstd * lnw[ch] + lnb[ch];
        q_in[orow + ch] = f2b(o);
    }
}

// ---------------- flash attention: block = (qtile of 64, h, b); 4 waves x 16 queries ----------
#define KP 104
#define VP 72
#define PP 72
#define SCALE 0.10206207261596575f
__global__ __launch_bounds__(256) void attn_kernel(const u16* __restrict__ Q,
                                                   const u16* __restrict__ Km,
                                                   const u16* __restrict__ Vm,
                                                   u16* __restrict__ O) {
    __shared__ __align__(16) u16 lK[64 * KP];
    __shared__ __align__(16) u16 lV[96 * VP];       // lV[feat][key]
    __shared__ __align__(16) u16 lP[4 * 16 * PP];   // per-wave P tiles
    int tid = threadIdx.x, lane = tid & 63, w = tid >> 6;
    int b = blockIdx.z, h = blockIdx.y, qt = blockIdx.x;
    const int lr = lane & 15, kg = lane >> 4;

    long qrow = ((long)b * 1024 + qt * 64 + w * 16 + lr) * 768 + h * 96;
    short8 aq[3];
    for (int ks = 0; ks < 3; ks++) aq[ks] = *(const short8*)&Q[qrow + ks * 32 + kg * 8];

    floatx4 acco[6] = {};
    float mrun[4], lrun[4];
    for (int r = 0; r < 4; r++) { mrun[r] = -1e30f; lrun[r] = 0.f; }

    long kvbase = ((long)b * 1024) * 768 + h * 96;
    for (int kt = 0; kt < 16; kt++) {
        // stage K tile [64 keys][96 f] and V tile transposed [96 f][64 keys]
        for (int e = tid; e < 768; e += 256) {
            int krow = e / 12, fs = e % 12;
            long g = kvbase + (long)(kt * 64 + krow) * 768 + fs * 8;
            short8 kv = *(const short8*)&Km[g];
            *(short8*)&lK[krow * KP + fs * 8] = kv;
            short8 vv = *(const short8*)&Vm[g];
            for (int i = 0; i < 8; i++) lV[(fs * 8 + i) * VP + krow] = (u16)vv[i];
        }
        __syncthreads();

        // S = Q K^T  (16 q x 64 keys per wave)
        floatx4 accs[4] = {};
        for (int ni = 0; ni < 4; ni++)
            for (int ks = 0; ks < 3; ks++) {
                short8 bk = *(const short8*)&lK[(ni * 16 + lr) * KP + ks * 32 + kg * 8];
                accs[ni] = __builtin_amdgcn_mfma_f32_16x16x32_bf16(aq[ks], bk, accs[ni], 0, 0, 0);
            }

        // online softmax (row m = kg*4 + r, spread across 16 lanes as columns)
        for (int r = 0; r < 4; r++) {
            float s0 = accs[0][r] * SCALE, s1 = accs[1][r] * SCALE;
            float s2 = accs[2][r] * SCALE, s3 = accs[3][r] * SCALE;
            float mt = fmaxf(fmaxf(s0, s1), fmaxf(s2, s3));
            for (int off = 1; off < 16; off <<= 1) mt = fmaxf(mt, __shfl_xor(mt, off));
            float mnew = fmaxf(mrun[r], mt);
            float corr = __expf(mrun[r] - mnew);
            float p0 = __expf(s0 - mnew), p1 = __expf(s1 - mnew);
            float p2 = __expf(s2 - mnew), p3 = __expf(s3 - mnew);
            float rsum = p0 + p1 + p2 + p3;
            for (int off = 1; off < 16; off <<= 1) rsum += __shfl_xor(rsum, off);
            lrun[r] = lrun[r] * corr + rsum;
            mrun[r] = mnew;
            for (int nb = 0; nb < 6; nb++) acco[nb][r] *= corr;
            int prow = w * 16 + kg * 4 + r;
            lP[prow * PP + 0 + lr] = f2b(p0);
            lP[prow * PP + 16 + lr] = f2b(p1);
            lP[prow * PP + 32 + lr] = f2b(p2);
            lP[prow * PP + 48 + lr] = f2b(p3);
        }
        __syncthreads();

        // O += P V
        short8 ap0 = *(const short8*)&lP[(w * 16 + lr) * PP + kg * 8];
        short8 ap1 = *(const short8*)&lP[(w * 16 + lr) * PP + 32 + kg * 8];
        for (int nb = 0; nb < 6; nb++) {
            short8 bv0 = *(const short8*)&lV[(nb * 16 + lr) * VP + kg * 8];
            short8 bv1 = *(const short8*)&lV[(nb * 16 + lr) * VP + 32 + kg * 8];
            acco[nb] = __builtin_amdgcn_mfma_f32_16x16x32_bf16(ap0, bv0, acco[nb], 0, 0, 0);
            acco[nb] = __builtin_amdgcn_mfma_f32_16x16x32_bf16(ap1, bv1, acco[nb], 0, 0, 0);
        }
        __syncthreads();
    }

    long obase = ((long)b * 1024 + qt * 64 + w * 16) * 768 + h * 96;
    for (int nb = 0; nb < 6; nb++)
        for (int r = 0; r < 4; r++) {
            float val = acco[nb][r] / lrun[r];
            O[obase + (long)(kg * 4 + r) * 768 + nb * 16 + lr] = f2b(val);
        }
}

// ---------------- LayerNorm over last dim, in-place fp32 on d_out (eps 1e-5) ----------------
__global__ __launch_bounds__(256) void ln2_inplace(float* __restrict__ o,
                                                   const float* __restrict__ lnw,
                                                   const float* __restrict__ lnb) {
    long row = (long)blockIdx.y * 1024 + blockIdx.x;
    long base = row * 768;
    int tid = threadIdx.x;
    float v[3], s = 0.f, sq = 0.f;
    for (int j = 0; j < 3; j++) {
        int ch = tid + j * 256;
        v[j] = o[base + ch];
        s += v[j];
        sq += v[j] * v[j];
    }
    __shared__ float rs[4], rq[4];
    for (int off = 32; off >= 1; off >>= 1) {
        s += __shfl_down(s, off);
        sq += __shfl_down(sq, off);
    }
    int lane = tid & 63, wid = tid >> 6;
    if (lane == 0) { rs[wid] = s; rq[wid] = sq; }
    __syncthreads();
    if (tid == 0) {
        rs[0] = rs[0] + rs[1] + rs[2] + rs[3];
        rq[0] = rq[0] + rq[1] + rq[2] + rq[3];
    }
    __syncthreads();
    float mean = rs[0] * (1.f / 768.f);
    float var = rq[0] * (1.f / 768.f) - mean * mean;
    float rstd = rsqrtf(var + 1e-5f);
    for (int j = 0; j < 3; j++) {
        int ch = tid + j * 256;
        float out = (v[j] - mean) * rstd * lnw[ch] + lnb[ch];
        o[base + ch] = out;
    }
}

extern "C" void kernel_launch(void* const* d_in, const int* in_sizes, int n_in,
                              void* d_out, int out_size, void* d_ws, size_t ws_size,
                              hipStream_t stream) {
    const float* x       = (const float*)d_in[0];   // (8,32,32,768) -> kv_in (8192,768)
    const float* clip    = (const float*)d_in[1];   // (8,1024,16,16)
    const float* conv_w  = (const float*)d_in[2];   // (1024,768)
    const float* conv_b  = (const float*)d_in[3];
    const float* ln1_w   = (const float*)d_in[4];
    const float* ln1_b   = (const float*)d_in[5];
    const float* wq      = (const float*)d_in[6];
    const float* bq      = (const float*)d_in[7];
    const float* wk      = (const float*)d_in[8];
    const float* bk      = (const float*)d_in[9];
    const float* wv      = (const float*)d_in[10];
    const float* bv      = (const float*)d_in[11];
    const float* wo      = (const float*)d_in[12];
    const float* bo      = (const float*)d_in[13];
    const float* ln2_w   = (const float*)d_in[14];
    const float* ln2_b   = (const float*)d_in[15];
    float* out = (float*)d_out;

    u16* ws = (u16*)d_ws;
    u16* clipT   = ws;                           // 8 x 256 x 1024   = 2,097,152
    u16* convwT  = clipT + 2097152;              // 768 x 1024       =   786,432
    u16* wqT     = convwT + 786432;              // 768 x 768        =   589,824
    u16* wkT     = wqT + 589824;
    u16* wvT     = wkT + 589824;
    u16* woT     = wvT + 589824;
    u16* t_lo    = woT + 589824;                 // 8 x 256 x 768    = 1,572,864
    u16* q_in    = t_lo + 1572864;               // 8192 x 768 (reused as attn out)
    u16* qb      = q_in + 6291456;
    u16* kb2     = qb + 6291456;
    u16* vb2     = kb2 + 6291456;
    u16* attno   = q_in;                          // reuse q_in region after q-proj

    // 1) transposes (fp32 -> bf16)
    transpose_f2b<<<dim3(8, 32, 8), 256, 0, stream>>>(clip, clipT, 1024, 256, 262144, 262144);
    transpose_f2b<<<dim3(24, 32, 1), 256, 0, stream>>>(conv_w, convwT, 1024, 768, 0, 0);
    transpose_f2b<<<dim3(24, 24, 1), 256, 0, stream>>>(wq, wqT, 768, 768, 0, 0);
    transpose_f2b<<<dim3(24, 24, 1), 256, 0, stream>>>(wk, wkT, 768, 768, 0, 0);
    transpose_f2b<<<dim3(24, 24, 1), 256, 0, stream>>>(wv, wvT, 768, 768, 0, 0);
    transpose_f2b<<<dim3(24, 24, 1), 256, 0, stream>>>(wo, woT, 768, 768, 0, 0);

    // 2) conv at 16x16: t_lo = clipT @ conv_w + conv_b   (M=2048, K=1024, N=768)
    gemm128<0, 0><<<dim3(16, 6), 256, 0, stream>>>(clipT, convwT, conv_b, t_lo, 2048, 768, 1024);

    // 3) bilinear resize + channel-first LN -> q_in (8192 x 768)
    ln1_resize<<<dim3(32, 32, 8), 256, 0, stream>>>(t_lo, ln1_w, ln1_b, q_in);

    // 4) projections (M=8192, K=768, N=768); k/v read fp32 x directly
    gemm128<0, 0><<<dim3(64, 6), 256, 0, stream>>>(q_in, wqT, bq, qb, 8192, 768, 768);
    gemm128<1, 0><<<dim3(64, 6), 256, 0, stream>>>(x,    wkT, bk, kb2, 8192, 768, 768);
    gemm128<1, 0><<<dim3(64, 6), 256, 0, stream>>>(x,    wvT, bv, vb2, 8192, 768, 768);

    // 5) attention -> attno (reuses q_in region; q_in no longer needed)
    attn_kernel<<<dim3(16, 8, 8), 256, 0, stream>>>(qb, kb2, vb2, attno);

    // 6) out projection -> d_out (fp32)
    gemm128<0, 1><<<dim3(64, 6), 256, 0, stream>>>(attno, woT, bo, out, 8192, 768, 768);

    // 7) LayerNorm in-place on d_out
    ln2_inplace<<<dim3(1024, 8), 256, 0, stream>>>(out, ln2_w, ln2_b);
}

// Round 5
// 240.057 us; speedup vs baseline: 1.2172x; 1.2172x over previous
//
#include <hip/hip_runtime.h>
#include <hip/hip_bf16.h>

typedef __attribute__((ext_vector_type(8))) short short8;
typedef __attribute__((ext_vector_type(4))) float floatx4;
typedef unsigned short u16;

__device__ __forceinline__ float b2f(u16 u) {
    unsigned int x = ((unsigned int)u) << 16;
    float f;
    __builtin_memcpy(&f, &x, 4);
    return f;
}
__device__ __forceinline__ u16 f2b(float f) {
    unsigned int x;
    __builtin_memcpy(&x, &f, 4);
    unsigned int lsb = (x >> 16) & 1u;
    x += 0x7fffu + lsb;
    return (u16)(x >> 16);
}

// ------------- transpose fp32 -> bf16, batched: out[C][R] = bf16(in[R][C]) -------------
__global__ __launch_bounds__(256) void transpose_f2b(const float* __restrict__ in,
                                                     u16* __restrict__ out,
                                                     int R, int C, long ibs, long obs) {
    __shared__ float tile[32][33];
    int b = blockIdx.z;
    const float* ip = in + (long)b * ibs;
    u16* op = out + (long)b * obs;
    int c0 = blockIdx.x * 32, r0 = blockIdx.y * 32;
    int tx = threadIdx.x & 31, ty = threadIdx.x >> 5;  // ty in 0..7
    for (int j = 0; j < 32; j += 8)
        tile[ty + j][tx] = ip[(long)(r0 + ty + j) * C + c0 + tx];
    __syncthreads();
    for (int j = 0; j < 32; j += 8)
        op[(long)(c0 + ty + j) * R + r0 + tx] = f2b(tile[tx][ty + j]);
}

// ------------- per-head V transpose (bf16): vT[(b*8+h)*96 + f][s] = vb2[b*1024+s][h*96+f] ----
__global__ __launch_bounds__(256) void transpose_vhead(const u16* __restrict__ in,
                                                       u16* __restrict__ out) {
    __shared__ u16 tile[32][34];
    int z = blockIdx.z;          // b*8+h
    int b = z >> 3, h = z & 7;
    int s0 = blockIdx.x * 32, f0 = blockIdx.y * 32;
    int tx = threadIdx.x & 31, ty = threadIdx.x >> 5;
    const u16* ip = in + ((long)b * 1024) * 768 + h * 96;
    u16* op = out + ((long)z * 96) * 1024;
    for (int j = 0; j < 32; j += 8)
        tile[ty + j][tx] = ip[(long)(s0 + ty + j) * 768 + f0 + tx];
    __syncthreads();
    for (int j = 0; j < 32; j += 8)
        op[(long)(f0 + ty + j) * 1024 + s0 + tx] = tile[tx][ty + j];
}

// ---- GEMM: C[M][N] = A[M][K] @ Bt[N][K]^T + bias. A fp32 or bf16, C fp32 or bf16 ----
#define TP 40
template <int A_F32, int OUT_F32>
__global__ __launch_bounds__(256) void gemm_bt(const void* __restrict__ Av,
                                               const u16* __restrict__ Bt,
                                               const float* __restrict__ bias,
                                               void* __restrict__ Cv,
                                               int M, int N, int K) {
    __shared__ __align__(16) u16 lA[64 * TP];
    __shared__ __align__(16) u16 lB[64 * TP];
    int tid = threadIdx.x, lane = tid & 63, w = tid >> 6;
    int wr = w >> 1, wc = w & 1;
    int m0 = blockIdx.x * 64, n0 = blockIdx.y * 64;
    floatx4 acc[2][2] = {};
    int srow = tid >> 2, sseg = (tid & 3) * 8;
    const int lr = lane & 15, kb = (lane >> 4) * 8;
    for (int k0 = 0; k0 < K; k0 += 32) {
        if (A_F32) {
            const float* A = (const float*)Av;
            const float* ap = &A[(long)(m0 + srow) * K + k0 + sseg];
            float4 f0 = *(const float4*)ap;
            float4 f1 = *(const float4*)(ap + 4);
            short8 s;
            s[0] = (short)f2b(f0.x); s[1] = (short)f2b(f0.y);
            s[2] = (short)f2b(f0.z); s[3] = (short)f2b(f0.w);
            s[4] = (short)f2b(f1.x); s[5] = (short)f2b(f1.y);
            s[6] = (short)f2b(f1.z); s[7] = (short)f2b(f1.w);
            *(short8*)&lA[srow * TP + sseg] = s;
        } else {
            const u16* A = (const u16*)Av;
            *(short8*)&lA[srow * TP + sseg] =
                *(const short8*)&A[(long)(m0 + srow) * K + k0 + sseg];
        }
        *(short8*)&lB[srow * TP + sseg] =
            *(const short8*)&Bt[(long)(n0 + srow) * K + k0 + sseg];
        __syncthreads();
        short8 a0 = *(const short8*)&lA[(wr * 32 + lr) * TP + kb];
        short8 a1 = *(const short8*)&lA[(wr * 32 + 16 + lr) * TP + kb];
        short8 b0 = *(const short8*)&lB[(wc * 32 + lr) * TP + kb];
        short8 b1 = *(const short8*)&lB[(wc * 32 + 16 + lr) * TP + kb];
        acc[0][0] = __builtin_amdgcn_mfma_f32_16x16x32_bf16(a0, b0, acc[0][0], 0, 0, 0);
        acc[0][1] = __builtin_amdgcn_mfma_f32_16x16x32_bf16(a0, b1, acc[0][1], 0, 0, 0);
        acc[1][0] = __builtin_amdgcn_mfma_f32_16x16x32_bf16(a1, b0, acc[1][0], 0, 0, 0);
        acc[1][1] = __builtin_amdgcn_mfma_f32_16x16x32_bf16(a1, b1, acc[1][1], 0, 0, 0);
        __syncthreads();
    }
    for (int mi = 0; mi < 2; mi++)
        for (int ni = 0; ni < 2; ni++) {
            int n = n0 + wc * 32 + ni * 16 + lr;
            float bv = bias[n];
            for (int r = 0; r < 4; r++) {
                int m = m0 + wr * 32 + mi * 16 + (lane >> 4) * 4 + r;
                float cv = acc[mi][ni][r] + bv;
                if (OUT_F32) ((float*)Cv)[(long)m * N + n] = cv;
                else ((u16*)Cv)[(long)m * N + n] = f2b(cv);
            }
        }
}

// --------- fused bilinear-resize (16->32, half-pixel) + channel-first LN (eps 1e-6) ---------
__global__ __launch_bounds__(256) void ln1_resize(const u16* __restrict__ t_lo,
                                                  const float* __restrict__ lnw,
                                                  const float* __restrict__ lnb,
                                                  u16* __restrict__ q_in) {
    int b = blockIdx.z, oh = blockIdx.y, ow = blockIdx.x;
    float sy = oh * 0.5f - 0.25f;
    int iy = (int)floorf(sy);
    float fy = sy - (float)iy;
    int y0 = min(max(iy, 0), 15), y1 = min(max(iy + 1, 0), 15);
    float sx = ow * 0.5f - 0.25f;
    int ix = (int)floorf(sx);
    float fx = sx - (float)ix;
    int x0 = min(max(ix, 0), 15), x1 = min(max(ix + 1, 0), 15);
    float w00 = (1.f - fy) * (1.f - fx), w01 = (1.f - fy) * fx;
    float w10 = fy * (1.f - fx), w11 = fy * fx;
    long base = (long)b * 256 * 768;
    long i00 = base + (long)(y0 * 16 + x0) * 768;
    long i01 = base + (long)(y0 * 16 + x1) * 768;
    long i10 = base + (long)(y1 * 16 + x0) * 768;
    long i11 = base + (long)(y1 * 16 + x1) * 768;
    int tid = threadIdx.x;
    float v[3], s = 0.f, sq = 0.f;
    for (int j = 0; j < 3; j++) {
        int ch = tid + j * 256;
        float val = w00 * b2f(t_lo[i00 + ch]) + w01 * b2f(t_lo[i01 + ch]) +
                    w10 * b2f(t_lo[i10 + ch]) + w11 * b2f(t_lo[i11 + ch]);
        v[j] = val;
        s += val;
        sq += val * val;
    }
    __shared__ float rs[4], rq[4];
    for (int off = 32; off >= 1; off >>= 1) {
        s += __shfl_down(s, off);
        sq += __shfl_down(sq, off);
    }
    int lane = tid & 63, wid = tid >> 6;
    if (lane == 0) { rs[wid] = s; rq[wid] = sq; }
    __syncthreads();
    if (tid == 0) {
        rs[0] = rs[0] + rs[1] + rs[2] + rs[3];
        rq[0] = rq[0] + rq[1] + rq[2] + rq[3];
    }
    __syncthreads();
    float mean = rs[0] * (1.f / 768.f);
    float var = rq[0] * (1.f / 768.f) - mean * mean;
    float rstd = rsqrtf(var + 1e-6f);
    long orow = ((long)b * 1024 + oh * 32 + ow) * 768;
    for (int j = 0; j < 3; j++) {
        int ch = tid + j * 256;
        float o = (v[j] - mean) * rstd * lnw[ch] + lnb[ch];
        q_in[orow + ch] = f2b(o);
    }
}

// ---------------- flash attention: block = (qtile of 64, h, b); 4 waves x 16 queries ----------
// V comes pre-transposed (vT[b,h][96][1024]) so staging is pure b128 copies.
#define KP 104
#define VP 72
#define PP 72
#define SCALE 0.10206207261596575f
__global__ __launch_bounds__(256) void attn_kernel(const u16* __restrict__ Q,
                                                   const u16* __restrict__ Km,
                                                   const u16* __restrict__ Vt,
                                                   u16* __restrict__ O) {
    __shared__ __align__(16) u16 lK[64 * KP];
    __shared__ __align__(16) u16 lV[96 * VP];       // lV[feat][key]
    __shared__ __align__(16) u16 lP[4 * 16 * PP];   // per-wave P tiles
    int tid = threadIdx.x, lane = tid & 63, w = tid >> 6;
    int b = blockIdx.z, h = blockIdx.y, qt = blockIdx.x;
    const int lr = lane & 15, kg = lane >> 4;

    long qrow = ((long)b * 1024 + qt * 64 + w * 16 + lr) * 768 + h * 96;
    short8 aq[3];
    for (int ks = 0; ks < 3; ks++) aq[ks] = *(const short8*)&Q[qrow + ks * 32 + kg * 8];

    floatx4 acco[6] = {};
    float mrun[4], lrun[4];
    for (int r = 0; r < 4; r++) { mrun[r] = -1e30f; lrun[r] = 0.f; }

    long kvbase = ((long)b * 1024) * 768 + h * 96;
    long vtbase = ((long)(b * 8 + h)) * 96 * 1024;
    for (int kt = 0; kt < 16; kt++) {
        // stage K tile [64 keys][96 f] (row-major) -- b128 copies
        for (int e = tid; e < 768; e += 256) {
            int krow = e / 12, fs = e % 12;
            long g = kvbase + (long)(kt * 64 + krow) * 768 + fs * 8;
            *(short8*)&lK[krow * KP + fs * 8] = *(const short8*)&Km[g];
        }
        // stage V^T tile [96 f][64 keys] from vT -- b128 copies, conflict-free
        for (int e = tid; e < 768; e += 256) {
            int f = e >> 3, kc = (e & 7) * 8;
            *(short8*)&lV[f * VP + kc] =
                *(const short8*)&Vt[vtbase + (long)f * 1024 + kt * 64 + kc];
        }
        __syncthreads();

        // S = Q K^T  (16 q x 64 keys per wave)
        floatx4 accs[4] = {};
        for (int ni = 0; ni < 4; ni++)
            for (int ks = 0; ks < 3; ks++) {
                short8 bk = *(const short8*)&lK[(ni * 16 + lr) * KP + ks * 32 + kg * 8];
                accs[ni] = __builtin_amdgcn_mfma_f32_16x16x32_bf16(aq[ks], bk, accs[ni], 0, 0, 0);
            }

        // online softmax (row m = kg*4 + r, spread across 16 lanes as columns)
        for (int r = 0; r < 4; r++) {
            float s0 = accs[0][r] * SCALE, s1 = accs[1][r] * SCALE;
            float s2 = accs[2][r] * SCALE, s3 = accs[3][r] * SCALE;
            float mt = fmaxf(fmaxf(s0, s1), fmaxf(s2, s3));
            for (int off = 1; off < 16; off <<= 1) mt = fmaxf(mt, __shfl_xor(mt, off));
            float mnew = fmaxf(mrun[r], mt);
            float corr = __expf(mrun[r] - mnew);
            float p0 = __expf(s0 - mnew), p1 = __expf(s1 - mnew);
            float p2 = __expf(s2 - mnew), p3 = __expf(s3 - mnew);
            float rsum = p0 + p1 + p2 + p3;
            for (int off = 1; off < 16; off <<= 1) rsum += __shfl_xor(rsum, off);
            lrun[r] = lrun[r] * corr + rsum;
            mrun[r] = mnew;
            for (int nb = 0; nb < 6; nb++) acco[nb][r] *= corr;
            int prow = w * 16 + kg * 4 + r;
            lP[prow * PP + 0 + lr] = f2b(p0);
            lP[prow * PP + 16 + lr] = f2b(p1);
            lP[prow * PP + 32 + lr] = f2b(p2);
            lP[prow * PP + 48 + lr] = f2b(p3);
        }
        __syncthreads();

        // O += P V
        short8 ap0 = *(const short8*)&lP[(w * 16 + lr) * PP + kg * 8];
        short8 ap1 = *(const short8*)&lP[(w * 16 + lr) * PP + 32 + kg * 8];
        for (int nb = 0; nb < 6; nb++) {
            short8 bv0 = *(const short8*)&lV[(nb * 16 + lr) * VP + kg * 8];
            short8 bv1 = *(const short8*)&lV[(nb * 16 + lr) * VP + 32 + kg * 8];
            acco[nb] = __builtin_amdgcn_mfma_f32_16x16x32_bf16(ap0, bv0, acco[nb], 0, 0, 0);
            acco[nb] = __builtin_amdgcn_mfma_f32_16x16x32_bf16(ap1, bv1, acco[nb], 0, 0, 0);
        }
        __syncthreads();
    }

    long obase = ((long)b * 1024 + qt * 64 + w * 16) * 768 + h * 96;
    for (int nb = 0; nb < 6; nb++)
        for (int r = 0; r < 4; r++) {
            float val = acco[nb][r] / lrun[r];
            O[obase + (long)(kg * 4 + r) * 768 + nb * 16 + lr] = f2b(val);
        }
}

// ---------------- LayerNorm over last dim, in-place fp32 on d_out (eps 1e-5) ----------------
__global__ __launch_bounds__(256) void ln2_inplace(float* __restrict__ o,
                                                   const float* __restrict__ lnw,
                                                   const float* __restrict__ lnb) {
    long row = (long)blockIdx.y * 1024 + blockIdx.x;
    long base = row * 768;
    int tid = threadIdx.x;
    float v[3], s = 0.f, sq = 0.f;
    for (int j = 0; j < 3; j++) {
        int ch = tid + j * 256;
        v[j] = o[base + ch];
        s += v[j];
        sq += v[j] * v[j];
    }
    __shared__ float rs[4], rq[4];
    for (int off = 32; off >= 1; off >>= 1) {
        s += __shfl_down(s, off);
        sq += __shfl_down(sq, off);
    }
    int lane = tid & 63, wid = tid >> 6;
    if (lane == 0) { rs[wid] = s; rq[wid] = sq; }
    __syncthreads();
    if (tid == 0) {
        rs[0] = rs[0] + rs[1] + rs[2] + rs[3];
        rq[0] = rq[0] + rq[1] + rq[2] + rq[3];
    }
    __syncthreads();
    float mean = rs[0] * (1.f / 768.f);
    float var = rq[0] * (1.f / 768.f) - mean * mean;
    float rstd = rsqrtf(var + 1e-5f);
    for (int j = 0; j < 3; j++) {
        int ch = tid + j * 256;
        float out = (v[j] - mean) * rstd * lnw[ch] + lnb[ch];
        o[base + ch] = out;
    }
}

extern "C" void kernel_launch(void* const* d_in, const int* in_sizes, int n_in,
                              void* d_out, int out_size, void* d_ws, size_t ws_size,
                              hipStream_t stream) {
    const float* x       = (const float*)d_in[0];   // (8,32,32,768) -> kv_in (8192,768)
    const float* clip    = (const float*)d_in[1];   // (8,1024,16,16)
    const float* conv_w  = (const float*)d_in[2];   // (1024,768)
    const float* conv_b  = (const float*)d_in[3];
    const float* ln1_w   = (const float*)d_in[4];
    const float* ln1_b   = (const float*)d_in[5];
    const float* wq      = (const float*)d_in[6];
    const float* bq      = (const float*)d_in[7];
    const float* wk      = (const float*)d_in[8];
    const float* bk      = (const float*)d_in[9];
    const float* wv      = (const float*)d_in[10];
    const float* bv      = (const float*)d_in[11];
    const float* wo      = (const float*)d_in[12];
    const float* bo      = (const float*)d_in[13];
    const float* ln2_w   = (const float*)d_in[14];
    const float* ln2_b   = (const float*)d_in[15];
    float* out = (float*)d_out;

    u16* ws = (u16*)d_ws;
    u16* clipT   = ws;                           // 8 x 256 x 1024   = 2,097,152
    u16* convwT  = clipT + 2097152;              // 768 x 1024       =   786,432
    u16* wqT     = convwT + 786432;              // 768 x 768        =   589,824
    u16* wkT     = wqT + 589824;
    u16* wvT     = wkT + 589824;
    u16* woT     = wvT + 589824;
    u16* t_lo    = woT + 589824;                 // 8 x 256 x 768    = 1,572,864
    u16* q_in    = t_lo + 1572864;               // 8192 x 768 (reused as attn out)
    u16* qb      = q_in + 6291456;
    u16* kb2     = qb + 6291456;
    u16* vb2     = kb2 + 6291456;
    u16* attno   = q_in;                          // reuse q_in region after q-proj
    // vT (64 x 96 x 1024 = 6,291,456 u16) aliases [clipT .. t_lo] (6,815,744 u16),
    // all dead after the projections. woT is NOT in that span and is (re)built after attn.
    u16* vT      = ws;

    // 1) transposes (fp32 -> bf16) -- woT deferred until after attention (its slot
    //    lies outside the vT alias span, but keep order simple/correct anyway)
    transpose_f2b<<<dim3(8, 32, 8), 256, 0, stream>>>(clip, clipT, 1024, 256, 262144, 262144);
    transpose_f2b<<<dim3(24, 32, 1), 256, 0, stream>>>(conv_w, convwT, 1024, 768, 0, 0);
    transpose_f2b<<<dim3(24, 24, 1), 256, 0, stream>>>(wq, wqT, 768, 768, 0, 0);
    transpose_f2b<<<dim3(24, 24, 1), 256, 0, stream>>>(wk, wkT, 768, 768, 0, 0);
    transpose_f2b<<<dim3(24, 24, 1), 256, 0, stream>>>(wv, wvT, 768, 768, 0, 0);

    // 2) conv at 16x16: t_lo = clipT @ conv_w + conv_b   (M=2048, K=1024, N=768)
    gemm_bt<0, 0><<<dim3(32, 12), 256, 0, stream>>>(clipT, convwT, conv_b, t_lo, 2048, 768, 1024);

    // 3) bilinear resize + channel-first LN -> q_in (8192 x 768)
    ln1_resize<<<dim3(32, 32, 8), 256, 0, stream>>>(t_lo, ln1_w, ln1_b, q_in);

    // 4) projections (M=8192, K=768, N=768); k/v read fp32 x directly
    gemm_bt<0, 0><<<dim3(128, 12), 256, 0, stream>>>(q_in, wqT, bq, qb, 8192, 768, 768);
    gemm_bt<1, 0><<<dim3(128, 12), 256, 0, stream>>>(x,    wkT, bk, kb2, 8192, 768, 768);
    gemm_bt<1, 0><<<dim3(128, 12), 256, 0, stream>>>(x,    wvT, bv, vb2, 8192, 768, 768);

    // 4b) per-head V transpose into vT (aliases dead clipT..t_lo region)
    transpose_vhead<<<dim3(32, 3, 64), 256, 0, stream>>>(vb2, vT);

    // 5) attention -> attno (reuses q_in region; q_in no longer needed)
    attn_kernel<<<dim3(16, 8, 8), 256, 0, stream>>>(qb, kb2, vT, attno);

    // 6) transpose wo now (woT slot untouched by vT alias), then out projection -> d_out
    transpose_f2b<<<dim3(24, 24, 1), 256, 0, stream>>>(wo, woT, 768, 768, 0, 0);
    gemm_bt<0, 1><<<dim3(128, 12), 256, 0, stream>>>(attno, woT, bo, out, 8192, 768, 768);

    // 7) LayerNorm in-place on d_out
    ln2_inplace<<<dim3(1024, 8), 256, 0, stream>>>(out, ln2_w, ln2_b);
}